// Round 7
// baseline (89.021 us; speedup 1.0000x reference)
//
#include <hip/hip_runtime.h>
#include <hip/hip_bf16.h>
#include <math.h>

#define NROWS 16384
#define DIN   784
#define DZ    100
#define NS    10
#define NCT   16           // 16 col-tiles x 16 = 256 cols (200 real + 56 zero pad)
#define KTILES 25          // 25 * 32 = 800 >= 784, tail frags zeroed
#define BND_THR 45.0f

typedef unsigned short ushort_t;
typedef short bf16x8 __attribute__((ext_vector_type(8)));
typedef float f32x4  __attribute__((ext_vector_type(4)));

#define AS1 __attribute__((address_space(1)))
#define AS3 __attribute__((address_space(3)))

// ws layout (float offsets):
//  [0..199]   colsum softplus (atomic)   [200] pv log-sum (atomic)   [201] Dkl
//  [208..8047]  y2[s][i] = y * log2e     [8064..9063] z[s][d]
//  [9600..16000) yfrag: y2 B-frags bf16, 25*64*8 ushorts (25.6 KB)
//  [16384..]  Wb: bf16 fragment-swizzled W, 25*16*512 ushorts (400 KB)
#define WS_Y2 208
#define WS_Z  8064
#define WS_YF 9600
#define WS_WB 16384

__device__ __forceinline__ float softplusf(float v) {
    return fmaxf(v, 0.f) + log1pf(__expf(-fabsf(v)));
}
__device__ __forceinline__ unsigned pack2(float lo, float hi) {
    float2 f2; f2.x = lo; f2.y = hi;
    __hip_bfloat162 h2 = __float22bfloat162_rn(f2);
    return *reinterpret_cast<unsigned*>(&h2);
}

// ---- W -> bf16, pre-swizzled to MFMA B-fragment order ----
// Wb[((kt*16 + ct)*64 + l)*8 + j] = W[ct*16 + (l&15)][kt*32 + (l>>4)*8 + j]
__global__ __launch_bounds__(256) void wb2_kernel(
    const float* __restrict__ W0, const float* __restrict__ W1, ushort_t* __restrict__ Wb)
{
    int t = blockIdx.x * 256 + threadIdx.x;
    if (t >= KTILES * NCT * 64) return;
    int kt = t >> 10;
    int r  = t & 1023;
    int ct = r >> 6, l = r & 63;
    int col = ct * 16 + (l & 15);
    int k0  = kt * 32 + (l >> 4) * 8;
    uint4 o = make_uint4(0u, 0u, 0u, 0u);
    if (col < 200 && k0 < DIN) {           // frag-aligned tail zeroed
        const float* src = (col < 100 ? W0 + (size_t)col * DIN
                                      : W1 + (size_t)(col - 100) * DIN) + k0;
        float4 a = *(const float4*)src;
        float4 b = *(const float4*)(src + 4);
        o.x = pack2(a.x, a.y); o.y = pack2(a.z, a.w);
        o.z = pack2(b.x, b.y); o.w = pack2(b.z, b.w);
    }
    *(uint4*)(Wb + (size_t)t * 8) = o;
}

// ---- MFMA column-sum of softplus(x@W.T + b) ----
// 512 blocks x 512 thr (8 waves = 4 rowgroups x 2 tilegroups). Block = 64 rows x
// 8 col-tiles (one half). x staged per K-step via glds with m173 source swizzle
// (slot = row*8 + ((chunk+row)&7)) -> linear glds dest, conflict-free b128 A-reads.
// W frags direct from L2 (coalesced), register double-buffered. 1 barrier/step.
__global__ __launch_bounds__(512, 4) void colmean_mfma(
    const float* __restrict__ x, const ushort_t* __restrict__ Wb,
    const float* __restrict__ b0, const float* __restrict__ b1,
    float* __restrict__ ws)
{
    __shared__ float xs[2][2048];          // 64 rows x 32 floats, slot-swizzled; 8 KB each
    const int tid = threadIdx.x;
    const int lane = tid & 63, w = tid >> 6;
    const int rg = w & 3, tg = w >> 2;

    int b = blockIdx.x;                    // XCD-bijective: 512 = 8 * 64
    int logical = (b & 7) * 64 + (b >> 3);
    const int strip = logical >> 1, half = logical & 1;

    // stage mapping: slot = tid; row = tid>>3, chunk c = ((tid&7) - row) & 7
    const int srow = tid >> 3;
    const int sc   = ((tid & 7) - srow) & 7;
    const float* xsrc_row = x + (size_t)(strip * 64 + srow) * DIN;

    // A-frag read slots (float offsets): lane's row R, k-chunk kc
    const int R  = rg * 16 + (lane & 15);
    const int kc = lane >> 4;
    const int rs0 = (R * 8 + ((2 * kc + R) & 7)) * 4;
    const int rs1 = (R * 8 + ((2 * kc + 1 + R) & 7)) * 4;

    f32x4 acc[4];
#pragma unroll
    for (int jj = 0; jj < 4; ++jj) acc[jj] = (f32x4){0.f, 0.f, 0.f, 0.f};

    auto stage = [&](int kt, int buf) {
        int f = kt * 32 + sc * 4;
        if (f + 4 > DIN) f = 0;            // junk ok: W frags zero at k>=784
        __builtin_amdgcn_global_load_lds(
            (const AS1 unsigned*)(xsrc_row + f),
            (AS3 unsigned*)(&xs[buf][w * 256]), 16, 0, 0);
    };
    auto wload = [&](int kt, uint4 (&wb)[4]) {
#pragma unroll
        for (int jj = 0; jj < 4; ++jj)
            wb[jj] = *(const uint4*)(Wb +
                ((size_t)((kt * NCT + half * 8 + tg * 4 + jj) * 64) + lane) * 8);
    };
    auto compute = [&](int buf, const uint4 (&wb)[4]) {
        f32x4 xa = *(const f32x4*)(&xs[buf][rs0]);
        f32x4 xb = *(const f32x4*)(&xs[buf][rs1]);
        bf16x8 af; unsigned* p = (unsigned*)&af;
        p[0] = pack2(xa[0], xa[1]); p[1] = pack2(xa[2], xa[3]);
        p[2] = pack2(xb[0], xb[1]); p[3] = pack2(xb[2], xb[3]);
#pragma unroll
        for (int jj = 0; jj < 4; ++jj)
            acc[jj] = __builtin_amdgcn_mfma_f32_16x16x32_bf16(
                af, *(const bf16x8*)&wb[jj], acc[jj], 0, 0, 0);
    };

    uint4 wA[4], wB[4];
    stage(0, 0); wload(0, wA);
    __syncthreads();
#pragma unroll 1
    for (int i = 0; i < 12; ++i) {
        stage(2 * i + 1, 1); wload(2 * i + 1, wB);
        __builtin_amdgcn_sched_barrier(0);
        compute(0, wA);
        __syncthreads();
        stage(2 * i + 2, 0); wload(2 * i + 2, wA);
        __builtin_amdgcn_sched_barrier(0);
        compute(1, wB);
        __syncthreads();
    }
    compute(0, wA);                        // kt = 24

    // epilogue: softplus+bias, per-wave 16-row reduce, atomic per column
    const int jcol = lane & 15;
#pragma unroll
    for (int jj = 0; jj < 4; ++jj) {
        int j = (half * 8 + tg * 4 + jj) * 16 + jcol;
        float bias = (j < 100) ? b0[j] : ((j < 200) ? b1[j - 100] : 0.f);
        float v = 0.f;
#pragma unroll
        for (int r = 0; r < 4; ++r) v += softplusf(acc[jj][r] + bias);
        v += __shfl_xor(v, 16);
        v += __shfl_xor(v, 32);
        if ((lane >> 4) == 0 && j < 200) atomicAdd(&ws[j], v);
    }
}

// ---- mean/cov, z, Dkl (single block) ----
__global__ __launch_bounds__(256) void middle_kernel(
    const float* __restrict__ eps, float* __restrict__ ws)
{
    __shared__ float red[256];
    const int tid = threadIdx.x;
    float contrib = 0.f;
    if (tid < DZ) {
        const float inv = 1.f / (float)NROWS;
        float mm = ws[tid] * inv;
        float cc = ws[100 + tid] * inv;
        contrib = 0.5f * __logf(cc);
#pragma unroll
        for (int s = 0; s < NS; ++s) {
            float e = eps[s * DZ + tid];
            float zz = mm + cc * e;
            ws[WS_Z + s * DZ + tid] = zz;
            contrib += (0.5f * cc * e * e - 0.5f * zz * zz) * (1.f / NS);
        }
    }
    red[tid] = contrib;
    __syncthreads();
    for (int off = 128; off > 0; off >>= 1) {
        if (tid < off) red[tid] += red[tid + off];
        __syncthreads();
    }
    if (tid == 0) ws[201] = red[0];
}

// ---- y2 = (z @ W2.T + b2) * log2e ----
__global__ __launch_bounds__(256) void y2_kernel(
    const float* __restrict__ W2, const float* __restrict__ b2,
    float* __restrict__ ws)
{
    int wid  = (int)((blockIdx.x * 256 + threadIdx.x) >> 6);
    int lane = threadIdx.x & 63;
    if (wid >= NS * DIN) return;
    int s = wid / DIN, i = wid % DIN;
    const float* zz = ws + WS_Z + s * DZ;
    const float* wr = W2 + (size_t)i * DZ;
    float p = 0.f;
    for (int d = lane; d < DZ; d += 64) p += zz[d] * wr[d];
#pragma unroll
    for (int off = 32; off > 0; off >>= 1) p += __shfl_xor(p, off);
    if (lane == 0) ws[WS_Y2 + wid] = (p + b2[i]) * 1.4426950408889634f;
}

// ---- pack y2 into MFMA B-fragment order (bf16), zero-padded ----
__global__ __launch_bounds__(256) void yfrag_kernel(
    const float* __restrict__ ws, ushort_t* yfp)
{
    int t = blockIdx.x * 256 + threadIdx.x;
    if (t >= KTILES * 64) return;
    int kt = t >> 6, l = t & 63;
    int ss = l & 15, k0 = kt * 32 + (l >> 4) * 8;
    uint4 o = make_uint4(0u, 0u, 0u, 0u);
    if (ss < NS && k0 + 8 <= DIN) {
        const float* src = ws + WS_Y2 + (size_t)ss * DIN + k0;
        float4 a = *(const float4*)src;
        float4 b = *(const float4*)(src + 4);
        o.x = pack2(a.x, a.y); o.y = pack2(a.z, a.w);
        o.z = pack2(b.x, b.y); o.w = pack2(b.z, b.w);
    }
    *(uint4*)(yfp + (size_t)t * 8) = o;
}

// ---- sum over (b,s) of log(prod_i sigmoid((2x-1)*y) + 1e-3) ----
// MFMA-certified bound: sum_i max(u,0) = 0.5*(n.y + |n|.|y|), u=(1-2x)*y2 (log2).
// bnd >= 45 => p < 2^-43 << ulp(0.001)/2 => term == ln(0.001) exactly.
// 1024 blocks x 4 waves; block = one 16-row tile; waves K-split by rounds
// (round r: wave w does kt=4r+w); x staged 4 kts/round via swizzled glds.
__global__ __launch_bounds__(256, 4) void pv_kernel(
    const float* __restrict__ x, const float* ws,
    const ushort_t* yfp, float* out_sum)
{
    __shared__ float xs[2][2048];          // 16 rows x 128 floats slot-swizzled; 8 KB each
    __shared__ float red[4][64][8];
    const int tid = threadIdx.x;
    const int lane = tid & 63, w = tid >> 6;

    int b = blockIdx.x;                    // XCD-bijective: 1024 = 8 * 128
    const int tile = (b & 7) * 128 + (b >> 3);

    // stage mapping: slots tid and tid+256: row = s>>5, chunk c = ((s&31)-row)&31
    const int r0s = tid >> 5,         c0s = ((tid & 31) - r0s) & 31;
    const int r1s = (tid + 256) >> 5, c1s = (((tid + 256) & 31) - r1s) & 31;
    const float* xt0 = x + (size_t)(tile * 16 + r0s) * DIN;
    const float* xt1 = x + (size_t)(tile * 16 + r1s) * DIN;

    const int R = lane & 15, kc = lane >> 4;
    const int rs0 = (R * 32 + ((w * 8 + 2 * kc + R) & 31)) * 4;
    const int rs1 = (R * 32 + ((w * 8 + 2 * kc + 1 + R) & 31)) * 4;

    f32x4 acc0 = (f32x4){0.f, 0.f, 0.f, 0.f};
    f32x4 acc1 = (f32x4){0.f, 0.f, 0.f, 0.f};

    auto stage = [&](int r, int buf) {
        int f0 = r * 128 + c0s * 4; if (f0 + 4 > DIN) f0 = 0;
        int f1 = r * 128 + c1s * 4; if (f1 + 4 > DIN) f1 = 0;
        __builtin_amdgcn_global_load_lds(
            (const AS1 unsigned*)(xt0 + f0),
            (AS3 unsigned*)(&xs[buf][w * 256]), 16, 0, 0);
        __builtin_amdgcn_global_load_lds(
            (const AS1 unsigned*)(xt1 + f1),
            (AS3 unsigned*)(&xs[buf][1024 + w * 256]), 16, 0, 0);
    };
    auto compute = [&](int r, int buf) {
        int kt = 4 * r + w;
        if (kt <= 24) {
            uint4 fyu = *(const uint4*)(yfp + ((size_t)(kt * 64 + lane)) * 8);
            f32x4 xa = *(const f32x4*)(&xs[buf][rs0]);
            f32x4 xb = *(const f32x4*)(&xs[buf][rs1]);
            bf16x8 nf; unsigned* p = (unsigned*)&nf;
            p[0] = pack2(1.f - 2.f * xa[0], 1.f - 2.f * xa[1]);
            p[1] = pack2(1.f - 2.f * xa[2], 1.f - 2.f * xa[3]);
            p[2] = pack2(1.f - 2.f * xb[0], 1.f - 2.f * xb[1]);
            p[3] = pack2(1.f - 2.f * xb[2], 1.f - 2.f * xb[3]);
            bf16x8 na; unsigned* q = (unsigned*)&na;
            q[0] = p[0] & 0x7FFF7FFFu; q[1] = p[1] & 0x7FFF7FFFu;
            q[2] = p[2] & 0x7FFF7FFFu; q[3] = p[3] & 0x7FFF7FFFu;
            uint4 fau;
            fau.x = fyu.x & 0x7FFF7FFFu; fau.y = fyu.y & 0x7FFF7FFFu;
            fau.z = fyu.z & 0x7FFF7FFFu; fau.w = fyu.w & 0x7FFF7FFFu;
            acc0 = __builtin_amdgcn_mfma_f32_16x16x32_bf16(
                nf, *(const bf16x8*)&fyu, acc0, 0, 0, 0);
            acc1 = __builtin_amdgcn_mfma_f32_16x16x32_bf16(
                na, *(const bf16x8*)&fau, acc1, 0, 0, 0);
        }
    };

    stage(0, 0);
    __syncthreads();
#pragma unroll 1
    for (int i = 0; i < 3; ++i) {
        stage(2 * i + 1, 1);
        __builtin_amdgcn_sched_barrier(0);
        compute(2 * i, 0);
        __syncthreads();
        stage(2 * i + 2, 0);
        __builtin_amdgcn_sched_barrier(0);
        compute(2 * i + 1, 1);
        __syncthreads();
    }
    compute(6, 0);

#pragma unroll
    for (int r = 0; r < 4; ++r) {
        red[w][lane][r]     = acc0[r];
        red[w][lane][4 + r] = acc1[r];
    }
    __syncthreads();

    if (w == 0) {
        const int s = lane & 15;
        const float L001 = -6.90775527898f;    // ln(0.001f)
        float bnd[4];
#pragma unroll
        for (int r = 0; r < 4; ++r) {
            float s0 = red[0][lane][r] + red[1][lane][r] + red[2][lane][r] + red[3][lane][r];
            float s1 = red[0][lane][4 + r] + red[1][lane][4 + r]
                     + red[2][lane][4 + r] + red[3][lane][4 + r];
            bnd[r] = 0.5f * (s0 + s1);
        }
        float wsum;
        bool lslow = (s < NS) &&
            (fminf(fminf(bnd[0], bnd[1]), fminf(bnd[2], bnd[3])) < BND_THR);
        unsigned long long m = __ballot(lslow);
        if (m == 0ull) {
            wsum = 160.f * L001;               // 16 rows x 10 samples, all certified
        } else {
            int nslow = 0;
            float slowsum = 0.f;
#pragma unroll
            for (int r = 0; r < 4; ++r) {
                unsigned long long mr = __ballot((s < NS) && (bnd[r] < BND_THR));
                nslow += (int)__popcll(mr);
                while (mr) {
                    int src = (int)__ffsll(mr) - 1; mr &= (mr - 1);
                    int ss = src & 15;
                    int rrow = tile * 16 + (src >> 4) * 4 + r;
                    const float* xq = x + (size_t)rrow * DIN;
                    const float* yq = ws + WS_Y2 + (size_t)ss * DIN;
                    float a = 0.f;
                    for (int i = lane; i < DIN; i += 64)
                        a -= __builtin_amdgcn_logf(
                            1.f + __builtin_amdgcn_exp2f((1.f - 2.f * xq[i]) * yq[i]));
#pragma unroll
                    for (int off = 32; off > 0; off >>= 1) a += __shfl_xor(a, off);
                    slowsum += __logf(__builtin_amdgcn_exp2f(a) + 0.001f);
                }
            }
            wsum = (float)(160 - nslow) * L001 + slowsum;
        }
        if (lane == 0) atomicAdd(out_sum, wsum);
    }
}

// ---- final scalar ----
__global__ void final_kernel(const float* __restrict__ ws, float* __restrict__ out)
{
    float E = ws[200] * (1.f / ((float)NROWS * (float)NS));
    out[0] = -(E + ws[201]);
}

extern "C" void kernel_launch(void* const* d_in, const int* in_sizes, int n_in,
                              void* d_out, int out_size, void* d_ws, size_t ws_size,
                              hipStream_t stream)
{
    const float* x   = (const float*)d_in[0];
    const float* W0  = (const float*)d_in[1];
    const float* b0  = (const float*)d_in[2];
    const float* W1  = (const float*)d_in[3];
    const float* b1  = (const float*)d_in[4];
    const float* W2  = (const float*)d_in[5];
    const float* b2  = (const float*)d_in[6];
    const float* eps = (const float*)d_in[7];
    float* out = (float*)d_out;
    float* ws  = (float*)d_ws;
    ushort_t* Wb  = (ushort_t*)(ws + WS_WB);
    ushort_t* yfp = (ushort_t*)(ws + WS_YF);

    hipMemsetAsync(ws, 0, 512 * sizeof(float), stream);
    wb2_kernel<<<(KTILES * NCT * 64 + 255) / 256, 256, 0, stream>>>(W0, W1, Wb);
    colmean_mfma<<<512, 512, 0, stream>>>(x, Wb, b0, b1, ws);
    middle_kernel<<<1, 256, 0, stream>>>(eps, ws);
    y2_kernel<<<(NS * DIN * 64) / 256, 256, 0, stream>>>(W2, b2, ws);
    yfrag_kernel<<<(KTILES * 64 + 255) / 256, 256, 0, stream>>>(ws, yfp);
    pv_kernel<<<1024, 256, 0, stream>>>(x, ws, yfp, ws + 200);
    final_kernel<<<1, 1, 0, stream>>>(ws, out);
}

// Round 8
// 88.155 us; speedup vs baseline: 1.0098x; 1.0098x over previous
//
#include <hip/hip_runtime.h>
#include <hip/hip_bf16.h>
#include <math.h>

#define NROWS 16384
#define DIN   784
#define DZ    100
#define NS    10
#define NCT   16           // 16 col-tiles x 16 = 256 cols (200 real + 56 zero pad)
#define KTILES 25          // 25 * 32 = 800 >= 784, tail frags zeroed
#define BND_THR 45.0f

typedef unsigned short ushort_t;
typedef short bf16x8 __attribute__((ext_vector_type(8)));
typedef float f32x4  __attribute__((ext_vector_type(4)));

#define AS1 __attribute__((address_space(1)))
#define AS3 __attribute__((address_space(3)))

// ws layout (float offsets):
//  [0..199]   colsum softplus (atomic)   [200] pv log-sum (atomic)   [201] Dkl
//  [208..8047]  y2[s][i] = y * log2e     [8064..9063] z[s][d]
//  [9600..16000) yfrag: y2 B-frags bf16, 25*64*8 ushorts
//  [16384..]  Wb: bf16 fragment-swizzled W, 25*16*512 ushorts (400 KB)
#define WS_Y2 208
#define WS_Z  8064
#define WS_YF 9600
#define WS_WB 16384

__device__ __forceinline__ float softplusf(float v) {
    return fmaxf(v, 0.f) + log1pf(__expf(-fabsf(v)));
}
__device__ __forceinline__ unsigned pack2(float lo, float hi) {
    float2 f2; f2.x = lo; f2.y = hi;
    __hip_bfloat162 h2 = __float22bfloat162_rn(f2);
    return *reinterpret_cast<unsigned*>(&h2);
}
__device__ __forceinline__ void glds16(const float* src, void* dst) {
    __builtin_amdgcn_global_load_lds((const AS1 unsigned*)src, (AS3 unsigned*)dst, 16, 0, 0);
}
__device__ __forceinline__ void glds16u(const ushort_t* src, void* dst) {
    __builtin_amdgcn_global_load_lds((const AS1 unsigned*)src, (AS3 unsigned*)dst, 16, 0, 0);
}

// ---- W -> bf16, pre-swizzled to MFMA B-fragment order ----
// Wb[((kt*16 + ct)*64 + l)*8 + j] = W[ct*16 + (l&15)][kt*32 + (l>>4)*8 + j]
__global__ __launch_bounds__(256) void wb2_kernel(
    const float* __restrict__ W0, const float* __restrict__ W1, ushort_t* __restrict__ Wb)
{
    int t = blockIdx.x * 256 + threadIdx.x;
    if (t >= KTILES * NCT * 64) return;
    int kt = t >> 10;
    int r  = t & 1023;
    int ct = r >> 6, l = r & 63;
    int col = ct * 16 + (l & 15);
    int k0  = kt * 32 + (l >> 4) * 8;
    uint4 o = make_uint4(0u, 0u, 0u, 0u);
    if (col < 200 && k0 < DIN) {
        const float* src = (col < 100 ? W0 + (size_t)col * DIN
                                      : W1 + (size_t)(col - 100) * DIN) + k0;
        float4 a = *(const float4*)src;
        float4 b = *(const float4*)(src + 4);
        o.x = pack2(a.x, a.y); o.y = pack2(a.z, a.w);
        o.z = pack2(b.x, b.y); o.w = pack2(b.z, b.w);
    }
    *(uint4*)(Wb + (size_t)t * 8) = o;
}

// ---- MFMA column-sum of softplus(x@W.T + b) ----
// 1024 blocks x 256 thr (4 waves = 4 rowgroups). Block = 64 rows x 4 col-tiles.
// x + W staged via glds; counted vmcnt(3) (T4) so next-step loads stay in flight
// across the raw s_barriers; compute never waits a full drain.
__global__ __launch_bounds__(256, 4) void colmean_mfma(
    const float* __restrict__ x, const ushort_t* __restrict__ Wb,
    const float* __restrict__ b0, const float* __restrict__ b1,
    float* __restrict__ ws)
{
    __shared__ float    xs[2][2048];   // 64 rows x 8 slot-swizzled chunks; 8 KB/buf
    __shared__ ushort_t wt[2][2048];   // 4 tiles x 1 KB; 4 KB/buf
    const int tid = threadIdx.x;
    const int lane = tid & 63, w = tid >> 6;

    int b = blockIdx.x;                // XCD-bijective: 1024 = 8 * 128
    int logical = (b & 7) * 128 + (b >> 3);
    const int strip = logical >> 2, q = logical & 3;

    // x stage: slot s in {tid, tid+256}: row = s>>3, c = s&7, chunk = (c-row)&7
    const int r0 = tid >> 3,         c0 = ((tid & 7) - r0) & 7;
    const int r1 = (tid + 256) >> 3, c1 = (((tid + 256) & 7) - r1) & 7;
    const float* xrow0 = x + (size_t)(strip * 64 + r0) * DIN;
    const float* xrow1 = x + (size_t)(strip * 64 + r1) * DIN;

    // A-frag read slots: row R, chunk 2kc(+1), swizzled
    const int R  = w * 16 + (lane & 15);
    const int kc = lane >> 4;
    const int rsA = R * 32 + ((2 * kc + R) & 7) * 4;
    const int rsB = R * 32 + ((2 * kc + 1 + R) & 7) * 4;

    f32x4 acc[4];
#pragma unroll
    for (int jj = 0; jj < 4; ++jj) acc[jj] = (f32x4){0.f, 0.f, 0.f, 0.f};

    auto stage = [&](int kt, int buf) {
        int f0 = kt * 32 + c0 * 4; if (f0 + 4 > DIN) f0 = 0;   // junk ok: W zero there
        int f1 = kt * 32 + c1 * 4; if (f1 + 4 > DIN) f1 = 0;
        glds16(xrow0 + f0, &xs[buf][tid * 4]);
        glds16(xrow1 + f1, &xs[buf][tid * 4 + 1024]);
        glds16u(Wb + (size_t)(kt * NCT + q * 4) * 512 + tid * 8, &wt[buf][tid * 8]);
    };
    auto compute = [&](int buf) {
        f32x4 xa = *(const f32x4*)(&xs[buf][rsA]);
        f32x4 xb = *(const f32x4*)(&xs[buf][rsB]);
        bf16x8 af; unsigned* p = (unsigned*)&af;
        p[0] = pack2(xa[0], xa[1]); p[1] = pack2(xa[2], xa[3]);
        p[2] = pack2(xb[0], xb[1]); p[3] = pack2(xb[2], xb[3]);
#pragma unroll
        for (int jj = 0; jj < 4; ++jj) {
            bf16x8 bf = *(const bf16x8*)(&wt[buf][jj * 512 + lane * 8]);
            acc[jj] = __builtin_amdgcn_mfma_f32_16x16x32_bf16(af, bf, acc[jj], 0, 0, 0);
        }
    };

    stage(0, 0);
#pragma unroll 1
    for (int kt = 0; kt < KTILES; ++kt) {
        const int cur = kt & 1;
        if (kt + 1 < KTILES) {
            stage(kt + 1, cur ^ 1);                       // 3 glds -> 6 outstanding
            asm volatile("s_waitcnt vmcnt(3)" ::: "memory");  // step-kt loads landed
        } else {
            asm volatile("s_waitcnt vmcnt(0)" ::: "memory");
        }
        __builtin_amdgcn_s_barrier();                     // buf[kt] full for all waves
        compute(cur);
        __builtin_amdgcn_sched_barrier(0);                // MFMAs stay before release
        __builtin_amdgcn_s_barrier();                     // buf[kt] free for kt+2
    }

    // epilogue: softplus+bias, per-wave 16-row reduce, atomic per column
    const int jcol = lane & 15;
#pragma unroll
    for (int jj = 0; jj < 4; ++jj) {
        int j = (q * 4 + jj) * 16 + jcol;
        float bias = (j < 100) ? b0[j] : ((j < 200) ? b1[j - 100] : 0.f);
        float v = 0.f;
#pragma unroll
        for (int r = 0; r < 4; ++r) v += softplusf(acc[jj][r] + bias);
        v += __shfl_xor(v, 16);
        v += __shfl_xor(v, 32);
        if ((lane >> 4) == 0 && j < 200) atomicAdd(&ws[j], v);
    }
}

// ---- mean/cov, z, Dkl (single block) ----
__global__ __launch_bounds__(256) void middle_kernel(
    const float* __restrict__ eps, float* __restrict__ ws)
{
    __shared__ float red[256];
    const int tid = threadIdx.x;
    float contrib = 0.f;
    if (tid < DZ) {
        const float inv = 1.f / (float)NROWS;
        float mm = ws[tid] * inv;
        float cc = ws[100 + tid] * inv;
        contrib = 0.5f * __logf(cc);
#pragma unroll
        for (int s = 0; s < NS; ++s) {
            float e = eps[s * DZ + tid];
            float zz = mm + cc * e;
            ws[WS_Z + s * DZ + tid] = zz;
            contrib += (0.5f * cc * e * e - 0.5f * zz * zz) * (1.f / NS);
        }
    }
    red[tid] = contrib;
    __syncthreads();
    for (int off = 128; off > 0; off >>= 1) {
        if (tid < off) red[tid] += red[tid + off];
        __syncthreads();
    }
    if (tid == 0) ws[201] = red[0];
}

// ---- y2 = (z @ W2.T + b2) * log2e; writes f32 row AND bf16 B-fragment ----
__global__ __launch_bounds__(256) void y2_kernel(
    const float* __restrict__ W2, const float* __restrict__ b2,
    float* __restrict__ ws, ushort_t* __restrict__ yfp)
{
    int wid  = (int)((blockIdx.x * 256 + threadIdx.x) >> 6);
    int lane = threadIdx.x & 63;
    if (wid >= NS * DIN) return;
    int s = wid / DIN, i = wid % DIN;
    const float* zz = ws + WS_Z + s * DZ;
    const float* wr = W2 + (size_t)i * DZ;
    float p = 0.f;
    for (int d = lane; d < DZ; d += 64) p += zz[d] * wr[d];
#pragma unroll
    for (int off = 32; off > 0; off >>= 1) p += __shfl_xor(p, off);
    if (lane == 0) {
        float v = (p + b2[i]) * 1.4426950408889634f;
        ws[WS_Y2 + wid] = v;
        int kt = i >> 5, k = i & 31, ks2 = k >> 3, j = k & 7;
        int l = ks2 * 16 + s;
        __hip_bfloat16 h = __float2bfloat16(v);
        yfp[((size_t)(kt * 64 + l)) * 8 + j] = *reinterpret_cast<ushort_t*>(&h);
    }
}

// ---- sum over (b,s) of log(prod_i sigmoid((2x-1)*y) + 1e-3) ----
// MFMA-certified bound: sum_i max(u,0) = 0.5*(n.y + |n|.|y|), u=(1-2x)*y2 (log2).
// bnd >= 45 => p < 2^-43 << ulp(0.001)/2 => term == ln(0.001) exactly.
// 512 blocks x 4 waves (2 rowgroups x 2 K-parities); counted vmcnt(2) pipeline.
__global__ __launch_bounds__(256, 2) void pv_kernel(
    const float* __restrict__ x, const float* ws,
    const ushort_t* __restrict__ yfp, float* out_sum)
{
    __shared__ float    xs[2][2048];       // 2 kts x 32 rows x 8 chunks; 8 KB/buf
    __shared__ ushort_t yf[KTILES * 512];  // 25.6 KB, staged once
    __shared__ float red[4][64][8];
    const int tid = threadIdx.x;
    const int lane = tid & 63, w = tid >> 6;
    const int rg = w & 1, ks = w >> 1;

    int b = blockIdx.x;                    // XCD-bijective: 512 = 8 * 64
    const int tile32 = (b & 7) * 64 + (b >> 3);

    for (int idx = tid; idx < KTILES * 64; idx += 256)
        glds16u(yfp + (size_t)idx * 8, &yf[idx * 8]);

    // x stage: slot s in {tid, tid+256}: ktp = s>>8, row = (s>>3)&31, c = s&7
    const int srow = tid >> 3, sc = ((tid & 7) - srow) & 7;
    const float* xrow = x + (size_t)(tile32 * 32 + srow) * DIN;

    const int R  = rg * 16 + (lane & 15);
    const int kc = lane >> 4;
    const int rsA = (ks * 256 + R * 8 + ((2 * kc + R) & 7)) * 4;
    const int rsB = (ks * 256 + R * 8 + ((2 * kc + 1 + R) & 7)) * 4;

    f32x4 acc0 = (f32x4){0.f, 0.f, 0.f, 0.f};
    f32x4 acc1 = (f32x4){0.f, 0.f, 0.f, 0.f};

    auto stage = [&](int r, int buf) {     // stages kts 2r, 2r+1
        int k0 = (2 * r) * 32 + sc * 4;
        if (2 * r > 24 || k0 + 4 > DIN) k0 = 0;        // junk ok: yf zero / kt skipped
        int k1 = (2 * r + 1) * 32 + sc * 4;
        if (2 * r + 1 > 24 || k1 + 4 > DIN) k1 = 0;
        glds16(xrow + k0, &xs[buf][tid * 4]);
        glds16(xrow + k1, &xs[buf][tid * 4 + 1024]);
    };
    auto compute = [&](int kt, int buf) {
        uint4 fyu = *(const uint4*)(&yf[(size_t)kt * 512 + lane * 8]);
        f32x4 xa = *(const f32x4*)(&xs[buf][rsA]);
        f32x4 xb = *(const f32x4*)(&xs[buf][rsB]);
        bf16x8 nf; unsigned* p = (unsigned*)&nf;
        p[0] = pack2(1.f - 2.f * xa[0], 1.f - 2.f * xa[1]);
        p[1] = pack2(1.f - 2.f * xa[2], 1.f - 2.f * xa[3]);
        p[2] = pack2(1.f - 2.f * xb[0], 1.f - 2.f * xb[1]);
        p[3] = pack2(1.f - 2.f * xb[2], 1.f - 2.f * xb[3]);
        bf16x8 na; unsigned* q = (unsigned*)&na;
        q[0] = p[0] & 0x7FFF7FFFu; q[1] = p[1] & 0x7FFF7FFFu;
        q[2] = p[2] & 0x7FFF7FFFu; q[3] = p[3] & 0x7FFF7FFFu;
        uint4 fau;
        fau.x = fyu.x & 0x7FFF7FFFu; fau.y = fyu.y & 0x7FFF7FFFu;
        fau.z = fyu.z & 0x7FFF7FFFu; fau.w = fyu.w & 0x7FFF7FFFu;
        acc0 = __builtin_amdgcn_mfma_f32_16x16x32_bf16(nf, *(const bf16x8*)&fyu, acc0, 0, 0, 0);
        acc1 = __builtin_amdgcn_mfma_f32_16x16x32_bf16(na, *(const bf16x8*)&fau, acc1, 0, 0, 0);
    };

    stage(0, 0);
    __syncthreads();                       // drains yf + stage(0) once (prologue only)
#pragma unroll 1
    for (int r = 0; r < 13; ++r) {
        const int cur = r & 1;
        if (r < 12) {
            stage(r + 1, cur ^ 1);
            asm volatile("s_waitcnt vmcnt(2)" ::: "memory");
        } else {
            asm volatile("s_waitcnt vmcnt(0)" ::: "memory");
        }
        __builtin_amdgcn_s_barrier();
        int kt = 2 * r + ks;
        if (kt < KTILES) compute(kt, cur);
        __builtin_amdgcn_sched_barrier(0);
        __builtin_amdgcn_s_barrier();
    }

#pragma unroll
    for (int r = 0; r < 4; ++r) {
        red[w][lane][r]     = acc0[r];
        red[w][lane][4 + r] = acc1[r];
    }
    __syncthreads();

    if (w < 2) {                           // wave w handles rowgroup rg = w
        const int s = lane & 15;
        const float L001 = -6.90775527898f;    // ln(0.001f)
        float bnd[4];
#pragma unroll
        for (int r = 0; r < 4; ++r) {
            float s0 = red[w][lane][r]     + red[w + 2][lane][r];
            float s1 = red[w][lane][4 + r] + red[w + 2][lane][4 + r];
            bnd[r] = 0.5f * (s0 + s1);
        }
        float wsum;
        bool lslow = (s < NS) &&
            (fminf(fminf(bnd[0], bnd[1]), fminf(bnd[2], bnd[3])) < BND_THR);
        unsigned long long m = __ballot(lslow);
        if (m == 0ull) {
            wsum = 160.f * L001;           // 16 rows x 10 samples, all certified
        } else {
            int nslow = 0;
            float slowsum = 0.f;
#pragma unroll
            for (int r = 0; r < 4; ++r) {
                unsigned long long mr = __ballot((s < NS) && (bnd[r] < BND_THR));
                nslow += (int)__popcll(mr);
                while (mr) {
                    int src = (int)__ffsll(mr) - 1; mr &= (mr - 1);
                    int ss = src & 15;
                    int rrow = tile32 * 32 + w * 16 + (src >> 4) * 4 + r;
                    const float* xq = x + (size_t)rrow * DIN;
                    const float* yq = ws + WS_Y2 + (size_t)ss * DIN;
                    float a = 0.f;
                    for (int i = lane; i < DIN; i += 64)
                        a -= __builtin_amdgcn_logf(
                            1.f + __builtin_amdgcn_exp2f((1.f - 2.f * xq[i]) * yq[i]));
#pragma unroll
                    for (int off = 32; off > 0; off >>= 1) a += __shfl_xor(a, off);
                    slowsum += __logf(__builtin_amdgcn_exp2f(a) + 0.001f);
                }
            }
            wsum = (float)(160 - nslow) * L001 + slowsum;
        }
        if (lane == 0) atomicAdd(out_sum, wsum);
    }
}

// ---- final scalar ----
__global__ void final_kernel(const float* __restrict__ ws, float* __restrict__ out)
{
    float E = ws[200] * (1.f / ((float)NROWS * (float)NS));
    out[0] = -(E + ws[201]);
}

extern "C" void kernel_launch(void* const* d_in, const int* in_sizes, int n_in,
                              void* d_out, int out_size, void* d_ws, size_t ws_size,
                              hipStream_t stream)
{
    const float* x   = (const float*)d_in[0];
    const float* W0  = (const float*)d_in[1];
    const float* b0  = (const float*)d_in[2];
    const float* W1  = (const float*)d_in[3];
    const float* b1  = (const float*)d_in[4];
    const float* W2  = (const float*)d_in[5];
    const float* b2  = (const float*)d_in[6];
    const float* eps = (const float*)d_in[7];
    float* out = (float*)d_out;
    float* ws  = (float*)d_ws;
    ushort_t* Wb  = (ushort_t*)(ws + WS_WB);
    ushort_t* yfp = (ushort_t*)(ws + WS_YF);

    hipMemsetAsync(ws, 0, 16000 * sizeof(float), stream);   // sums + y2 + z + yfrag
    wb2_kernel<<<(KTILES * NCT * 64 + 255) / 256, 256, 0, stream>>>(W0, W1, Wb);
    colmean_mfma<<<1024, 256, 0, stream>>>(x, Wb, b0, b1, ws);
    middle_kernel<<<1, 256, 0, stream>>>(eps, ws);
    y2_kernel<<<(NS * DIN * 64) / 256, 256, 0, stream>>>(W2, b2, ws, yfp);
    pv_kernel<<<512, 256, 0, stream>>>(x, ws, yfp, ws + 200);
    final_kernel<<<1, 1, 0, stream>>>(ws, out);
}